// Round 17
// baseline (153.024 us; speedup 1.0000x reference)
//
#include <hip/hip_runtime.h>
#include <hip/hip_bf16.h>

#define SEQ 4096
#define EMB 1024
#define HS 64

typedef __attribute__((ext_vector_type(8))) short bf16x8;
typedef __attribute__((ext_vector_type(4))) float f32x4;

__device__ __forceinline__ unsigned short f2b(float f) {
    union { float f; unsigned u; } v; v.f = f;
    unsigned r = v.u + 0x7fffu + ((v.u >> 16) & 1u);
    return (unsigned short)(r >> 16);
}
__device__ __forceinline__ unsigned int f2b2(float a, float b) {
    __hip_bfloat162 h = __float22bfloat162_rn(float2{a, b});   // RNE, matches f2b
    union { __hip_bfloat162 h; unsigned int u; } v; v.h = h; return v.u;
}
__device__ __forceinline__ float b2f(unsigned short h) {
    union { unsigned u; float f; } v; v.u = ((unsigned)h) << 16;
    return v.f;
}
// async global->LDS DMA, 16B/lane
template <typename T>
__device__ __forceinline__ void gll16(const T* g, void* l) {
    __builtin_amdgcn_global_load_lds(
        (const __attribute__((address_space(1))) unsigned int*)(g),
        (__attribute__((address_space(3))) unsigned int*)(l), 16, 0, 0);
}
// same, non-temporal (streaming data: don't evict L2 reuse set)
template <typename T>
__device__ __forceinline__ void gll16nt(const T* g, void* l) {
    __builtin_amdgcn_global_load_lds(
        (const __attribute__((address_space(1))) unsigned int*)(g),
        (__attribute__((address_space(3))) unsigned int*)(l), 16, 0, 2);
}

// ---------- W transpose + cast: Wt[192][1024] bf16; rows 0-63=Q (pre-scaled), 64-127=K, 128-191=V
__global__ __launch_bounds__(256) void wt_kernel(const float* __restrict__ Wq,
                                                 const float* __restrict__ Wk,
                                                 const float* __restrict__ Wv,
                                                 unsigned short* __restrict__ Wt) {
    int id = blockIdx.x * 256 + threadIdx.x;
    int mat = id >> 16;
    int rem = id & 65535;
    int k = rem >> 6;
    int n = rem & 63;
    const float* W = (mat == 0) ? Wq : (mat == 1) ? Wk : Wv;
    float scale = (mat == 0) ? 0.125f * 1.44269504f : 1.0f;   // fold 1/sqrt(64)*log2(e) into Q
    Wt[(mat * HS + n) * EMB + k] = f2b(W[k * HS + n] * scale);
}

// ---------- fused QKV projection: 32 rows x 192 cols, dbuf DMA; x streamed NT, Wt protected in L2
__global__ __launch_bounds__(256, 2) void proj_kernel(const float* __restrict__ x,
                                                      const unsigned short* __restrict__ Wt,
                                                      unsigned short* __restrict__ Qb,
                                                      unsigned short* __restrict__ Kb,
                                                      unsigned short* __restrict__ Vt) {
    __shared__ float xf[2][32 * 64];              // 2 x 8 KiB, chunk swizzle c^(row&15)
    __shared__ unsigned short wb[2][192 * 64];    // 2 x 24 KiB, chunk swizzle c^(row&7)
    const int tid = threadIdx.x;
    const int wave = tid >> 6, lane = tid & 63;
    const int col = lane & 15, quad = lane >> 4;
    const int m0 = blockIdx.x * 32;
    const int b = m0 >> 12, t0 = m0 & 4095;

    const int xr_in = lane >> 4;
    const int xc = lane & 15;
    const int wr_in = lane >> 3;
    const int wc = lane & 7;

    f32x4 acc[2][3];
    #pragma unroll
    for (int i = 0; i < 2; i++)
        #pragma unroll
        for (int j = 0; j < 3; j++) acc[i][j] = (f32x4){0.f, 0.f, 0.f, 0.f};

    auto stage = [&](int k0, int bufi) {
        #pragma unroll
        for (int t = 0; t < 2; t++) {
            int R = (wave + t * 4) * 4;
            int row = R + xr_in;
            gll16nt(x + (size_t)(m0 + row) * EMB + k0 + ((xc ^ (row & 15)) << 2),
                    &xf[bufi][R * 64]);
        }
        #pragma unroll
        for (int t = 0; t < 6; t++) {
            int R = (wave * 6 + t) * 8;
            int row = R + wr_in;
            gll16(Wt + (size_t)row * EMB + k0 + ((wc ^ (row & 7)) << 3),
                  &wb[bufi][R * 64]);
        }
    };

    stage(0, 0);
    int buf = 0;
    #pragma unroll 1
    for (int k0 = 0; k0 < EMB; k0 += 64) {
        __syncthreads();
        if (k0 + 64 < EMB) stage(k0 + 64, buf ^ 1);
        #pragma unroll
        for (int kc = 0; kc < 2; kc++) {
            const int q2 = quad + kc * 4;
            bf16x8 af[2], bfr[3];
            #pragma unroll
            for (int mt = 0; mt < 2; mt++) {
                int rr = mt * 16 + col;
                float4 lo = *(const float4*)&xf[buf][rr * 64 + (((2 * q2) ^ col) << 2)];
                float4 hi = *(const float4*)&xf[buf][rr * 64 + (((2 * q2 + 1) ^ col) << 2)];
                union { bf16x8 v; unsigned int u[4]; } A;
                A.u[0] = f2b2(lo.x, lo.y); A.u[1] = f2b2(lo.z, lo.w);
                A.u[2] = f2b2(hi.x, hi.y); A.u[3] = f2b2(hi.z, hi.w);
                af[mt] = A.v;
            }
            #pragma unroll
            for (int nt = 0; nt < 3; nt++) {
                int rn = wave * 48 + nt * 16 + col;
                bfr[nt] = *(const bf16x8*)&wb[buf][rn * 64 + ((q2 ^ (col & 7)) << 3)];
            }
            #pragma unroll
            for (int mt = 0; mt < 2; mt++)
                #pragma unroll
                for (int nt = 0; nt < 3; nt++)
                    acc[mt][nt] = __builtin_amdgcn_mfma_f32_16x16x32_bf16(af[mt], bfr[nt], acc[mt][nt], 0, 0, 0);
        }
        buf ^= 1;
    }

    #pragma unroll
    for (int mt = 0; mt < 2; mt++)
        #pragma unroll
        for (int nt = 0; nt < 3; nt++) {
            const int g = wave * 3 + nt;
            const int mat = g >> 2;
            const int ncol = (g & 3) * 16 + col;
            #pragma unroll
            for (int r = 0; r < 4; r++) {
                unsigned short val = f2b(acc[mt][nt][r]);
                int row = mt * 16 + quad * 4 + r;
                if (mat == 0)      __builtin_nontemporal_store(val, &Qb[(size_t)(m0 + row) * HS + ncol]);
                else if (mat == 1) __builtin_nontemporal_store(val, &Kb[(size_t)(m0 + row) * HS + ncol]);
                else               __builtin_nontemporal_store(val, &Vt[((size_t)b * HS + ncol) * SEQ + t0 + row]);
            }
        }
}

// ---------- flash attention (causal): 8-wave blocks, BM=128, dbuf DMA K/V; streams written NT ----------
// tile T: 2T+2 kv-steps; pieces of <=10; np(T)=T/5+1; grid 476
__global__ __launch_bounds__(512, 4) void attn_kernel(const unsigned short* __restrict__ Qb,
                                                      const unsigned short* __restrict__ Kb,
                                                      const unsigned short* __restrict__ Vt,
                                                      unsigned short* __restrict__ Opart,
                                                      float* __restrict__ Lpart,
                                                      float* __restrict__ out) {
    __shared__ unsigned short Kl[2][64 * 64];   // chunk swizzle c^(row&7)
    __shared__ unsigned short Vl[2][64 * 64];   // chunk swizzle c^(h&7)
    __shared__ unsigned short P_lds[8][16 * 72];
    const int tid = threadIdx.x;
    const int wave = tid >> 6, lane = tid & 63;
    const int col = lane & 15, quad = lane >> 4;
    const int bid = blockIdx.x;            // 0..475
    const int g = 118 - (bid >> 2);        // longest-first piece id
    const int b = bid & 3;
    int T = 0, accp = 0;
    for (;;) { int np = T / 5 + 1; if (accp + np > g) break; accp += np; T++; }
    const int piece = g - accp;
    const int np = T / 5 + 1;
    const int q0 = T << 7;
    const int s_beg = piece * 10;
    const int s_end = min(s_beg + 10, 2 * T + 2);

    const unsigned short* Kp = Kb + ((size_t)(b << 12)) * HS;
    const unsigned short* Vp = Vt + (size_t)b * HS * SEQ;

    bf16x8 qf[2];
    #pragma unroll
    for (int c = 0; c < 2; c++)
        qf[c] = *(const bf16x8*)(Qb + ((size_t)(b << 12) + q0 + wave * 16 + col) * HS + quad * 8 + c * 32);

    f32x4 o[4];
    float l[4];
    #pragma unroll
    for (int ct = 0; ct < 4; ct++) o[ct] = (f32x4){0.f, 0.f, 0.f, 0.f};
    #pragma unroll
    for (int r = 0; r < 4; r++) l[r] = 0.f;

    const int r_in = lane >> 3;
    const int ch = lane & 7;

    auto stage = [&](int s, int bufi) {
        const int kv0 = s << 6;
        int R = wave * 8;
        int row = R + r_in;
        gll16(Kp + (size_t)(kv0 + row) * HS + ((ch ^ (row & 7)) << 3), &Kl[bufi][R * 64]);
        gll16(Vp + (size_t)row * SEQ + kv0 + ((ch ^ (row & 7)) << 3), &Vl[bufi][R * 64]);
    };

    stage(s_beg, 0);
    int buf = 0;
    const int grb = (b << 12) + q0 + wave * 16;
    const int rgb = q0 + wave * 16 + quad * 4;
    unsigned short* Pl = P_lds[wave];

    #pragma unroll 1
    for (int s = s_beg; s < s_end; s++) {
        __syncthreads();
        if (s + 1 < s_end) stage(s + 1, buf ^ 1);
        const int kv0 = s << 6;

        f32x4 sacc[4];
        #pragma unroll
        for (int ct = 0; ct < 4; ct++) sacc[ct] = (f32x4){0.f, 0.f, 0.f, 0.f};
        #pragma unroll
        for (int ct = 0; ct < 4; ct++) {
            int n = ct * 16 + col;
            #pragma unroll
            for (int kc = 0; kc < 2; kc++) {
                bf16x8 kf = *(const bf16x8*)&Kl[buf][n * 64 + (((kc * 4 + quad) ^ (col & 7)) << 3)];
                sacc[ct] = __builtin_amdgcn_mfma_f32_16x16x32_bf16(qf[kc], kf, sacc[ct], 0, 0, 0);
            }
        }

        float p[4][4];
        #pragma unroll
        for (int ct = 0; ct < 4; ct++) {
            int cg = kv0 + ct * 16 + col;
            #pragma unroll
            for (int r = 0; r < 4; r++) {
                float e = __builtin_exp2f(sacc[ct][r]);
                e = (cg > rgb + r) ? 0.f : e;
                p[ct][r] = e;
                l[r] += e;
            }
        }

        #pragma unroll
        for (int ct = 0; ct < 4; ct++)
            #pragma unroll
            for (int r = 0; r < 4; r++)
                Pl[(quad * 4 + r) * 72 + ct * 16 + col] = f2b(p[ct][r]);
        bf16x8 pf[2];
        #pragma unroll
        for (int c = 0; c < 2; c++)
            pf[c] = *(const bf16x8*)&Pl[col * 72 + quad * 8 + c * 32];

        #pragma unroll
        for (int ct = 0; ct < 4; ct++) {
            int h = ct * 16 + col;
            #pragma unroll
            for (int kc = 0; kc < 2; kc++) {
                bf16x8 vf = *(const bf16x8*)&Vl[buf][h * 64 + (((kc * 4 + quad) ^ (col & 7)) << 3)];
                o[ct] = __builtin_amdgcn_mfma_f32_16x16x32_bf16(pf[kc], vf, o[ct], 0, 0, 0);
            }
        }
        buf ^= 1;
    }

    #pragma unroll
    for (int off = 1; off < 16; off <<= 1)
        #pragma unroll
        for (int r = 0; r < 4; r++)
            l[r] += __shfl_xor(l[r], off, 64);

    if (np == 1) {
        // single-piece tile (T<=4): direct output (stream -> NT)
        #pragma unroll
        for (int ct = 0; ct < 4; ct++)
            #pragma unroll
            for (int r = 0; r < 4; r++)
                __builtin_nontemporal_store(o[ct][r] / l[r],
                    &out[(size_t)(grb + quad * 4 + r) * HS + ct * 16 + col]);
    } else {
        // bf16 partials, NT (read once by comb; keep K/V resident in L2)
        const int widx = bid * 8 + wave;
        unsigned short* Op = Opart + (size_t)widx * 1024;
        #pragma unroll
        for (int ct = 0; ct < 4; ct++) {
            unsigned long long pv = (unsigned long long)f2b2(o[ct][0], o[ct][1])
                                  | ((unsigned long long)f2b2(o[ct][2], o[ct][3]) << 32);
            __builtin_nontemporal_store(pv, (unsigned long long*)(Op + ct * 256 + lane * 4));
        }
        if (col == 0) {
            #pragma unroll
            for (int r = 0; r < 4; r++)
                __builtin_nontemporal_store(l[r], &Lpart[widx * 16 + quad * 4 + r]);
        }
    }
}

// ---------- combine split-KV partials for T>=5: coalesced NT reads ----------
__global__ __launch_bounds__(256) void comb_kernel(const unsigned short* __restrict__ Opart,
                                                   const float* __restrict__ Lpart,
                                                   float* __restrict__ out) {
    const int bid = blockIdx.x;            // 864 = 4 b x 27 T x 8 wave
    const int b = bid & 3;
    const int idx = bid >> 2;              // 0..215
    const int T = 5 + (idx % 27);
    const int wave = idx / 27;             // 0..7
    const int tid = threadIdx.x;
    const int lane = tid & 63, ct = tid >> 6;
    const int col = lane & 15, quad = lane >> 4;

    const int q = T / 5, r5 = T % 5;
    const int base = T + 5 * q * (q - 1) / 2 + r5 * q;   // piece-id prefix for S=10
    const int np = q + 1;

    float acc[4] = {0.f, 0.f, 0.f, 0.f};
    float l[4] = {0.f, 0.f, 0.f, 0.f};
    for (int p = 0; p < np; p++) {
        int gg = base + p;
        int bidp = ((118 - gg) << 2) | b;
        int widx = bidp * 8 + wave;
        unsigned long long u = __builtin_nontemporal_load(
            (const unsigned long long*)(Opart + (size_t)widx * 1024 + ct * 256 + lane * 4));
        acc[0] += b2f((unsigned short)(u));
        acc[1] += b2f((unsigned short)(u >> 16));
        acc[2] += b2f((unsigned short)(u >> 32));
        acc[3] += b2f((unsigned short)(u >> 48));
        #pragma unroll
        for (int r = 0; r < 4; r++)
            l[r] += __builtin_nontemporal_load(&Lpart[widx * 16 + quad * 4 + r]);
    }
    const size_t rowb = (size_t)(b << 12) + (T << 7) + wave * 16 + quad * 4;
    #pragma unroll
    for (int r = 0; r < 4; r++)
        __builtin_nontemporal_store(acc[r] / l[r], &out[(rowb + r) * HS + ct * 16 + col]);
}

extern "C" void kernel_launch(void* const* d_in, const int* in_sizes, int n_in,
                              void* d_out, int out_size, void* d_ws, size_t ws_size,
                              hipStream_t stream) {
    const float* x  = (const float*)d_in[0];
    const float* Wk = (const float*)d_in[1];
    const float* Wq = (const float*)d_in[2];
    const float* Wv = (const float*)d_in[3];
    float* out = (float*)d_out;

    char* ws = (char*)d_ws;
    unsigned short* Wt = (unsigned short*)(ws);                 // 393216 B
    unsigned short* Qb = (unsigned short*)(ws + 393216);        // 2 MiB
    unsigned short* Kb = (unsigned short*)(ws + 2490368);       // 2 MiB
    unsigned short* Vt = (unsigned short*)(ws + 4587520);       // 2 MiB
    unsigned short* Opart = (unsigned short*)(ws + 6684672);    // 476*8*1024*2 = 7.80 MB
    float* Lpart          = (float*)(ws + 14483456);            // 476*8*16*4 = 243712 B

    wt_kernel<<<dim3(768), dim3(256), 0, stream>>>(Wq, Wk, Wv, Wt);
    proj_kernel<<<dim3(512), dim3(256), 0, stream>>>(x, Wt, Qb, Kb, Vt);
    attn_kernel<<<dim3(476), dim3(512), 0, stream>>>(Qb, Kb, Vt, Opart, Lpart, out);
    comb_kernel<<<dim3(864), dim3(256), 0, stream>>>(Opart, Lpart, out);
}

// Round 18
// 145.027 us; speedup vs baseline: 1.0551x; 1.0551x over previous
//
#include <hip/hip_runtime.h>

#define SEQ 4096
#define EMB 1024
#define HS 64

typedef __attribute__((ext_vector_type(8))) short bf16x8;
typedef __attribute__((ext_vector_type(4))) float f32x4;

__device__ __forceinline__ unsigned short f2b(float f) {
    union { float f; unsigned u; } v; v.f = f;
    unsigned r = v.u + 0x7fffu + ((v.u >> 16) & 1u);
    return (unsigned short)(r >> 16);
}
__device__ __forceinline__ float b2f(unsigned short h) {
    union { unsigned u; float f; } v; v.u = ((unsigned)h) << 16;
    return v.f;
}
// async global->LDS DMA, 16B/lane; LDS dst = wave-uniform base + lane*16
template <typename T>
__device__ __forceinline__ void gll16(const T* g, void* l) {
    __builtin_amdgcn_global_load_lds(
        (const __attribute__((address_space(1))) unsigned int*)(g),
        (__attribute__((address_space(3))) unsigned int*)(l), 16, 0, 0);
}

// ---------- W transpose + cast: Wt[192][1024] bf16; rows 0-63=Q (pre-scaled), 64-127=K, 128-191=V
__global__ __launch_bounds__(256) void wt_kernel(const float* __restrict__ Wq,
                                                 const float* __restrict__ Wk,
                                                 const float* __restrict__ Wv,
                                                 unsigned short* __restrict__ Wt) {
    int id = blockIdx.x * 256 + threadIdx.x;
    int mat = id >> 16;
    int rem = id & 65535;
    int k = rem >> 6;
    int n = rem & 63;
    const float* W = (mat == 0) ? Wq : (mat == 1) ? Wk : Wv;
    float scale = (mat == 0) ? 0.125f * 1.44269504f : 1.0f;   // fold 1/sqrt(64)*log2(e) into Q
    Wt[(mat * HS + n) * EMB + k] = f2b(W[k * HS + n] * scale);
}

// ---------- fused QKV projection (R12/R16-proven best): 32 rows x 192 cols, dbuf DMA staging ----------
__global__ __launch_bounds__(256, 2) void proj_kernel(const float* __restrict__ x,
                                                      const unsigned short* __restrict__ Wt,
                                                      unsigned short* __restrict__ Qb,
                                                      unsigned short* __restrict__ Kb,
                                                      unsigned short* __restrict__ Vt) {
    __shared__ float xf[2][32 * 64];              // 2 x 8 KiB, chunk swizzle c^(row&15)
    __shared__ unsigned short wb[2][192 * 64];    // 2 x 24 KiB, chunk swizzle c^(row&7)
    const int tid = threadIdx.x;
    const int wave = tid >> 6, lane = tid & 63;
    const int col = lane & 15, quad = lane >> 4;
    const int m0 = blockIdx.x * 32;
    const int b = m0 >> 12, t0 = m0 & 4095;

    const int xr_in = lane >> 4;
    const int xc = lane & 15;
    const int wr_in = lane >> 3;
    const int wc = lane & 7;

    f32x4 acc[2][3];
    #pragma unroll
    for (int i = 0; i < 2; i++)
        #pragma unroll
        for (int j = 0; j < 3; j++) acc[i][j] = (f32x4){0.f, 0.f, 0.f, 0.f};

    auto stage = [&](int k0, int bufi) {
        #pragma unroll
        for (int t = 0; t < 2; t++) {
            int R = (wave + t * 4) * 4;
            int row = R + xr_in;
            gll16(x + (size_t)(m0 + row) * EMB + k0 + ((xc ^ (row & 15)) << 2),
                  &xf[bufi][R * 64]);
        }
        #pragma unroll
        for (int t = 0; t < 6; t++) {
            int R = (wave * 6 + t) * 8;
            int row = R + wr_in;
            gll16(Wt + (size_t)row * EMB + k0 + ((wc ^ (row & 7)) << 3),
                  &wb[bufi][R * 64]);
        }
    };

    stage(0, 0);
    int buf = 0;
    #pragma unroll 1
    for (int k0 = 0; k0 < EMB; k0 += 64) {
        __syncthreads();
        if (k0 + 64 < EMB) stage(k0 + 64, buf ^ 1);
        #pragma unroll
        for (int kc = 0; kc < 2; kc++) {
            const int q2 = quad + kc * 4;
            bf16x8 af[2], bfr[3];
            #pragma unroll
            for (int mt = 0; mt < 2; mt++) {
                int rr = mt * 16 + col;
                float4 lo = *(const float4*)&xf[buf][rr * 64 + (((2 * q2) ^ col) << 2)];
                float4 hi = *(const float4*)&xf[buf][rr * 64 + (((2 * q2 + 1) ^ col) << 2)];
                bf16x8 a;
                a[0] = (short)f2b(lo.x); a[1] = (short)f2b(lo.y);
                a[2] = (short)f2b(lo.z); a[3] = (short)f2b(lo.w);
                a[4] = (short)f2b(hi.x); a[5] = (short)f2b(hi.y);
                a[6] = (short)f2b(hi.z); a[7] = (short)f2b(hi.w);
                af[mt] = a;
            }
            #pragma unroll
            for (int nt = 0; nt < 3; nt++) {
                int rn = wave * 48 + nt * 16 + col;
                bfr[nt] = *(const bf16x8*)&wb[buf][rn * 64 + ((q2 ^ (col & 7)) << 3)];
            }
            #pragma unroll
            for (int mt = 0; mt < 2; mt++)
                #pragma unroll
                for (int nt = 0; nt < 3; nt++)
                    acc[mt][nt] = __builtin_amdgcn_mfma_f32_16x16x32_bf16(af[mt], bfr[nt], acc[mt][nt], 0, 0, 0);
        }
        buf ^= 1;
    }

    #pragma unroll
    for (int mt = 0; mt < 2; mt++)
        #pragma unroll
        for (int nt = 0; nt < 3; nt++) {
            const int g = wave * 3 + nt;
            const int mat = g >> 2;
            const int ncol = (g & 3) * 16 + col;
            #pragma unroll
            for (int r = 0; r < 4; r++) {
                unsigned short val = f2b(acc[mt][nt][r]);
                int row = mt * 16 + quad * 4 + r;
                if (mat == 0)      Qb[(size_t)(m0 + row) * HS + ncol] = val;
                else if (mat == 1) Kb[(size_t)(m0 + row) * HS + ncol] = val;
                else               Vt[((size_t)b * HS + ncol) * SEQ + t0 + row] = val;
            }
        }
}

// ---------- flash attention (causal): 8-wave blocks, BM=128, TRIPLE-buffered DMA K/V ----------
// raw s_barrier + manual s_waitcnt vmcnt(2): 2-step DMA lookahead stays in flight across barriers.
// tile T: 2T+2 kv-steps; pieces of <=10; np(T)=T/5+1; grid 476 <= 512 slots (2 blocks/CU @ 66.5KB LDS)
__global__ __launch_bounds__(512, 4) void attn_kernel(const unsigned short* __restrict__ Qb,
                                                      const unsigned short* __restrict__ Kb,
                                                      const unsigned short* __restrict__ Vt,
                                                      unsigned short* __restrict__ Opart,
                                                      float* __restrict__ Lpart,
                                                      float* __restrict__ out) {
    __shared__ unsigned short Kl[3][64 * 64];   // chunk swizzle c^(row&7)
    __shared__ unsigned short Vl[3][64 * 64];   // chunk swizzle c^(h&7)
    __shared__ unsigned short P_lds[8][16 * 72];
    const int tid = threadIdx.x;
    const int wave = tid >> 6, lane = tid & 63;
    const int col = lane & 15, quad = lane >> 4;
    const int bid = blockIdx.x;            // 0..475
    const int g = 118 - (bid >> 2);        // longest-first piece id
    const int b = bid & 3;
    int T = 0, accp = 0;
    for (;;) { int np = T / 5 + 1; if (accp + np > g) break; accp += np; T++; }
    const int piece = g - accp;
    const int np = T / 5 + 1;
    const int q0 = T << 7;
    const int s_beg = piece * 10;
    const int s_end = min(s_beg + 10, 2 * T + 2);

    const unsigned short* Kp = Kb + ((size_t)(b << 12)) * HS;
    const unsigned short* Vp = Vt + (size_t)b * HS * SEQ;

    bf16x8 qf[2];
    #pragma unroll
    for (int c = 0; c < 2; c++)
        qf[c] = *(const bf16x8*)(Qb + ((size_t)(b << 12) + q0 + wave * 16 + col) * HS + quad * 8 + c * 32);

    f32x4 o[4];
    float l[4];
    #pragma unroll
    for (int ct = 0; ct < 4; ct++) o[ct] = (f32x4){0.f, 0.f, 0.f, 0.f};
    #pragma unroll
    for (int r = 0; r < 4; r++) l[r] = 0.f;

    const int r_in = lane >> 3;
    const int ch = lane & 7;

    auto stage = [&](int s, int bufi) {       // 2 DMA instrs per wave
        const int kv0 = s << 6;
        int R = wave * 8;
        int row = R + r_in;
        gll16(Kp + (size_t)(kv0 + row) * HS + ((ch ^ (row & 7)) << 3), &Kl[bufi][R * 64]);
        gll16(Vp + (size_t)row * SEQ + kv0 + ((ch ^ (row & 7)) << 3), &Vl[bufi][R * 64]);
    };

    // prologue: 2-step lookahead (4 DMA instrs outstanding)
    stage(s_beg, 0);
    stage(min(s_beg + 1, s_end - 1), 1);
    int bufr = 0;                              // buffer of step s: (s - s_beg) % 3
    const int grb = (b << 12) + q0 + wave * 16;
    const int rgb = q0 + wave * 16 + quad * 4;
    unsigned short* Pl = P_lds[wave];

    #pragma unroll 1
    for (int s = s_beg; s < s_end; s++) {
        // wait own step-s DMA (oldest 2 of <=4 outstanding), then barrier; s+1's stay in flight
        asm volatile("s_waitcnt vmcnt(2)\n\ts_barrier" ::: "memory");
        // issue step s+2 (clamped duplicate near the end -> uniform vmcnt bookkeeping; unread buffer)
        stage(min(s + 2, s_end - 1), (bufr + 2) % 3);
        const int kv0 = s << 6;

        f32x4 sacc[4];
        #pragma unroll
        for (int ct = 0; ct < 4; ct++) sacc[ct] = (f32x4){0.f, 0.f, 0.f, 0.f};
        #pragma unroll
        for (int ct = 0; ct < 4; ct++) {
            int n = ct * 16 + col;
            #pragma unroll
            for (int kc = 0; kc < 2; kc++) {
                bf16x8 kf = *(const bf16x8*)&Kl[bufr][n * 64 + (((kc * 4 + quad) ^ (col & 7)) << 3)];
                sacc[ct] = __builtin_amdgcn_mfma_f32_16x16x32_bf16(qf[kc], kf, sacc[ct], 0, 0, 0);
            }
        }

        float p[4][4];
        #pragma unroll
        for (int ct = 0; ct < 4; ct++) {
            int cg = kv0 + ct * 16 + col;
            #pragma unroll
            for (int r = 0; r < 4; r++) {
                float e = __builtin_exp2f(sacc[ct][r]);
                e = (cg > rgb + r) ? 0.f : e;
                p[ct][r] = e;
                l[r] += e;
            }
        }

        #pragma unroll
        for (int ct = 0; ct < 4; ct++)
            #pragma unroll
            for (int r = 0; r < 4; r++)
                Pl[(quad * 4 + r) * 72 + ct * 16 + col] = f2b(p[ct][r]);
        bf16x8 pf[2];
        #pragma unroll
        for (int c = 0; c < 2; c++)
            pf[c] = *(const bf16x8*)&Pl[col * 72 + quad * 8 + c * 32];

        #pragma unroll
        for (int ct = 0; ct < 4; ct++) {
            int h = ct * 16 + col;
            #pragma unroll
            for (int kc = 0; kc < 2; kc++) {
                bf16x8 vf = *(const bf16x8*)&Vl[bufr][h * 64 + (((kc * 4 + quad) ^ (col & 7)) << 3)];
                o[ct] = __builtin_amdgcn_mfma_f32_16x16x32_bf16(pf[kc], vf, o[ct], 0, 0, 0);
            }
        }
        bufr = (bufr == 2) ? 0 : bufr + 1;
    }

    #pragma unroll
    for (int off = 1; off < 16; off <<= 1)
        #pragma unroll
        for (int r = 0; r < 4; r++)
            l[r] += __shfl_xor(l[r], off, 64);

    if (np == 1) {
        // single-piece tile (T<=4): write output directly, no partials
        #pragma unroll
        for (int ct = 0; ct < 4; ct++)
            #pragma unroll
            for (int r = 0; r < 4; r++)
                out[(size_t)(grb + quad * 4 + r) * HS + ct * 16 + col] = o[ct][r] / l[r];
    } else {
        // bf16 partials (plain stores, proven fast)
        const int widx = bid * 8 + wave;
        unsigned short* Op = Opart + (size_t)widx * 1024;
        #pragma unroll
        for (int ct = 0; ct < 4; ct++) {
            ushort4 st;
            st.x = f2b(o[ct][0]); st.y = f2b(o[ct][1]);
            st.z = f2b(o[ct][2]); st.w = f2b(o[ct][3]);
            *(ushort4*)(Op + ct * 256 + lane * 4) = st;
        }
        if (col == 0) {
            #pragma unroll
            for (int r = 0; r < 4; r++)
                Lpart[widx * 16 + quad * 4 + r] = l[r];
        }
    }
}

// ---------- combine split-KV partials for T>=5 (np>=2): coalesced ushort4 reads ----------
__global__ __launch_bounds__(256) void comb_kernel(const unsigned short* __restrict__ Opart,
                                                   const float* __restrict__ Lpart,
                                                   float* __restrict__ out) {
    const int bid = blockIdx.x;            // 864 = 4 b x 27 T x 8 wave
    const int b = bid & 3;
    const int idx = bid >> 2;              // 0..215
    const int T = 5 + (idx % 27);
    const int wave = idx / 27;             // 0..7
    const int tid = threadIdx.x;
    const int lane = tid & 63, ct = tid >> 6;
    const int col = lane & 15, quad = lane >> 4;

    const int q = T / 5, r5 = T % 5;
    const int base = T + 5 * q * (q - 1) / 2 + r5 * q;   // piece-id prefix for S=10
    const int np = q + 1;

    float acc[4] = {0.f, 0.f, 0.f, 0.f};
    float l[4] = {0.f, 0.f, 0.f, 0.f};
    for (int p = 0; p < np; p++) {
        int gg = base + p;
        int bidp = ((118 - gg) << 2) | b;
        int widx = bidp * 8 + wave;
        ushort4 v = *(const ushort4*)(Opart + (size_t)widx * 1024 + ct * 256 + lane * 4);
        acc[0] += b2f(v.x); acc[1] += b2f(v.y);
        acc[2] += b2f(v.z); acc[3] += b2f(v.w);
        #pragma unroll
        for (int r = 0; r < 4; r++)
            l[r] += Lpart[widx * 16 + quad * 4 + r];
    }
    const size_t rowb = (size_t)(b << 12) + (T << 7) + wave * 16 + quad * 4;
    #pragma unroll
    for (int r = 0; r < 4; r++)
        out[(rowb + r) * HS + ct * 16 + col] = acc[r] / l[r];
}

extern "C" void kernel_launch(void* const* d_in, const int* in_sizes, int n_in,
                              void* d_out, int out_size, void* d_ws, size_t ws_size,
                              hipStream_t stream) {
    const float* x  = (const float*)d_in[0];
    const float* Wk = (const float*)d_in[1];
    const float* Wq = (const float*)d_in[2];
    const float* Wv = (const float*)d_in[3];
    float* out = (float*)d_out;

    char* ws = (char*)d_ws;
    unsigned short* Wt = (unsigned short*)(ws);                 // 393216 B
    unsigned short* Qb = (unsigned short*)(ws + 393216);        // 2 MiB
    unsigned short* Kb = (unsigned short*)(ws + 2490368);       // 2 MiB
    unsigned short* Vt = (unsigned short*)(ws + 4587520);       // 2 MiB
    unsigned short* Opart = (unsigned short*)(ws + 6684672);    // 476*8*1024*2 = 7.80 MB
    float* Lpart          = (float*)(ws + 14483456);            // 476*8*16*4 = 243712 B

    wt_kernel<<<dim3(768), dim3(256), 0, stream>>>(Wq, Wk, Wv, Wt);
    proj_kernel<<<dim3(512), dim3(256), 0, stream>>>(x, Wt, Qb, Kb, Vt);
    attn_kernel<<<dim3(476), dim3(512), 0, stream>>>(Qb, Kb, Vt, Opart, Lpart, out);
    comb_kernel<<<dim3(864), dim3(256), 0, stream>>>(Opart, Lpart, out);
}